// Round 13
// baseline (46.891 us; speedup 1.0000x reference)
//
#include <hip/hip_runtime.h>

// FeatureAttentionLayer: B=32, W=128, K=128, E=256, fp32 — fused, occupancy-2.
//   L[i][e] = sum_w x[b][w][i]*lin_w[e][w] + lin_b[e]
//   R[j][e] = sum_w x[b][w][j]*lin_w[e][128+w]
//   e[i][j] = 0.6(dL[i]+dR[j]) + sum_e 0.4a[e]|L+R| + bias   (LReLU identity)
//   att = softmax_j; out[b][w][i] = sigmoid(sum_j att[i][j]*x[b][w][j])
//
// Round-13: r12 fusion at 130KB LDS ran 1 block/CU with no staging prefetch —
// every barrier drained at 1 wave/SIMD. This version keeps all r11/r12-verified
// math (MFMA fragment layouts, swizzles, RNE pack, e-loop, softmax, phase2)
// but restructures to K2's proven schedule: 16-e chunks, double-buffered
// As2/Rs/Lt, next chunk's global loads issued BEFORE the barrier (fly under
// MFMA+e-loop), 2 barriers/chunk. LDS 78.5KB -> 2 blocks/CU, grid (32,16),
// 2 waves/SIMD.

typedef float v2f __attribute__((ext_vector_type(2)));
typedef float v4f __attribute__((ext_vector_type(4)));
typedef short bf16x8 __attribute__((ext_vector_type(8)));

__device__ __forceinline__ unsigned pack_bf16x2(float a, float b) {
    unsigned ua = __builtin_bit_cast(unsigned, a);
    unsigned ub = __builtin_bit_cast(unsigned, b);
    ua = (ua + 0x7FFFu + ((ua >> 16) & 1u)) >> 16;   // RNE f32->bf16
    ub = (ub + 0x7FFFu + ((ub >> 16) & 1u)) >> 16;
    return ua | (ub << 16);
}
__device__ __forceinline__ float bf2f(unsigned h) {
    unsigned u = h << 16;
    return __builtin_bit_cast(float, u);
}

// grid (32 b, 16 it of 8 i-rows), 256 thr (4 waves). 2 blocks/CU.
__global__ __launch_bounds__(256) void k_fused(
    const float* __restrict__ x, const float* __restrict__ lin_w,
    const float* __restrict__ lin_b, const float* __restrict__ a,
    const float* __restrict__ bias, float* __restrict__ out)
{
    __shared__ unsigned short xT[136 * 136];      // bf16 x[b] T+swz, rows 128-135 zero (37 KB)
    __shared__ unsigned short As2[2][16 * 264];   // bf16 lin_w chunk, dbuf (16.5 KB)
    __shared__ float Rs[2][16 * 132];             // f32 R chunk [e][j], dbuf (16.5 KB)
    __shared__ float Lt[2][16 * 18];              // f32 L chunk [e][i]+lin_b, dbuf (2.25 KB)
    __shared__ float att[8 * 132];                // (4.2 KB)
    __shared__ float as6[256], as4[256], lbs[256];// (3 KB)   total ~78.5 KB

    const int t = threadIdx.x;
    const int b = blockIdx.x, it = blockIdx.y;

    // ---- stage xT[k][w'] = bf16(x[b][w][k]), col-group swizzle g ^= (k>>3)&15 ----
    {
        const float* xg = x + b * 16384;
        #pragma unroll
        for (int q = 0; q < 8; ++q) {
            const int idx = t + q * 256;                 // 0..2047
            const int wp = idx >> 5;                     // w-pair 0..63
            const int k4 = (idx & 31) << 2;
            const v4f r0 = *(const v4f*)(xg + (2 * wp) * 128 + k4);
            const v4f r1 = *(const v4f*)(xg + (2 * wp + 1) * 128 + k4);
            const int g   = wp >> 2;
            const int off = (2 * wp) & 7;
            #pragma unroll
            for (int u = 0; u < 4; ++u) {
                const int k = k4 + u;
                const int gs = g ^ ((k >> 3) & 15);
                *(unsigned*)&xT[k * 136 + (gs << 3) + off] = pack_bf16x2(r0[u], r1[u]);
            }
        }
        // zero pad rows 128..135 (read by L B-frags of it=15; outputs discarded)
        #pragma unroll
        for (int q = 0; q < 3; ++q) {
            const int idx = t + q * 256;
            if (idx < 544) *(unsigned*)&xT[128 * 136 + idx * 2] = 0u;
        }
    }
    as6[t] = 0.6f * a[t];
    as4[t] = 0.4f * a[t];
    lbs[t] = lin_b[t];

    const int l = t & 63, wave = t >> 6;
    const int lr = l & 15, lg = l >> 4;
    const int jp = t & 31, iq = t >> 5;     // 1 i-row per thread (8 rows/block)
    const int j0 = jp * 4;
    const int i_base = it * 8;

    float acc0[4] = {};                     // sum 0.4a*|L+R| per jj
    float dr[4]  = {};                      // sum 0.6a*R per jj
    float dl0 = 0.f;                        // sum 0.6a*L for this row

    // ---- lin_w chunk prefetch: 16 rows x 256 cols f32 = 8 v2f per thread ----
    v2f pre[8];
#define WLOAD(c_) do {                                                      \
    _Pragma("unroll") for (int q = 0; q < 8; ++q) {                         \
        const int idx = t + q * 256;                                        \
        const int rr = idx >> 7, cp = idx & 127;                            \
        pre[q] = *(const v2f*)(lin_w + (size_t)((c_) * 16 + rr) * 256 + 2 * cp); \
    } } while (0)

    WLOAD(0);

    #pragma unroll 1
    for (int c = 0; c < 16; ++c) {
        const int cur = c & 1;
        // commit chunk c to As2[cur] (bf16)
        #pragma unroll
        for (int q = 0; q < 8; ++q) {
            const int idx = t + q * 256;
            const int rr = idx >> 7, cp = idx & 127;
            *(unsigned*)&As2[cur][rr * 264 + 2 * cp] = pack_bf16x2(pre[q].x, pre[q].y);
        }
        if (c < 15) WLOAD(c + 1);          // flies under MFMA + e-loop below
        __syncthreads();                   // As2[cur] ready (xT ready on c=0)

        // ---- MFMA: chunk = 16 e-rows; K = 128 w (4 kc). Per wave:
        //      R: j in [wave*32, wave*32+32) -> 2 frags x 4 kc = 8 MFMAs
        //      L: i in [i_base, i_base+16)   -> 1 frag  x 4 kc = 4 MFMAs
        {
            bf16x8 afL[4], afR[4];
            #pragma unroll
            for (int kc = 0; kc < 4; ++kc) {
                afL[kc] = *(const bf16x8*)&As2[cur][lr * 264 + kc * 32 + lg * 8];
                afR[kc] = *(const bf16x8*)&As2[cur][lr * 264 + 128 + kc * 32 + lg * 8];
            }
            v4f aL  = (v4f){0.f, 0.f, 0.f, 0.f};
            v4f aR0 = (v4f){0.f, 0.f, 0.f, 0.f};
            v4f aR1 = (v4f){0.f, 0.f, 0.f, 0.f};
            const int jr0 = wave * 32 + lr, jr1 = jr0 + 16;
            const int ir  = i_base + lr;
            #pragma unroll
            for (int kc = 0; kc < 4; ++kc) {
                const int g0 = kc * 4 + lg;
                const bf16x8 bR0 = *(const bf16x8*)&xT[jr0 * 136 + ((g0 ^ ((jr0 >> 3) & 15)) << 3)];
                const bf16x8 bR1 = *(const bf16x8*)&xT[jr1 * 136 + ((g0 ^ ((jr1 >> 3) & 15)) << 3)];
                const bf16x8 bL  = *(const bf16x8*)&xT[ir  * 136 + ((g0 ^ ((ir  >> 3) & 15)) << 3)];
                aR0 = __builtin_amdgcn_mfma_f32_16x16x32_bf16(afR[kc], bR0, aR0, 0, 0, 0);
                aR1 = __builtin_amdgcn_mfma_f32_16x16x32_bf16(afR[kc], bR1, aR1, 0, 0, 0);
                aL  = __builtin_amdgcn_mfma_f32_16x16x32_bf16(afL[kc], bL,  aL,  0, 0, 0);
            }
            // D row m = lg*4 + reg (e-local), D col n = fragbase + lr (r11-verified)
            #pragma unroll
            for (int j = 0; j < 4; ++j) {
                const int el = lg * 4 + j;
                Rs[cur][el * 132 + wave * 32 + lr]      = aR0[j];
                Rs[cur][el * 132 + wave * 32 + 16 + lr] = aR1[j];
                if (lr < 8) Lt[cur][el * 18 + lr] = aL[j] + lbs[c * 16 + el];
            }
        }
        __syncthreads();                   // Rs/Lt[cur] ready

        // ---- e-loop on chunk (4 groups of 4 e) ----
        #pragma unroll
        for (int g = 0; g < 4; ++g) {
            const int e0 = g * 4, eg = c * 16 + e0;
            v4f rv[4]; float lv[4];
            #pragma unroll
            for (int u = 0; u < 4; ++u) {
                rv[u] = *(const v4f*)&Rs[cur][(e0 + u) * 132 + j0];
                lv[u] = Lt[cur][(e0 + u) * 18 + iq];
            }
            const v4f a6v = *(const v4f*)&as6[eg];
            const v4f a4v = *(const v4f*)&as4[eg];
            #pragma unroll
            for (int u = 0; u < 4; ++u) {
                const float a6u = a6v[u], a4u = a4v[u], l0 = lv[u];
                dl0 = fmaf(a6u, l0, dl0);
                #pragma unroll
                for (int jj = 0; jj < 4; ++jj) {
                    const float r = rv[u][jj];
                    dr[jj]   = fmaf(a6u, r, dr[jj]);
                    acc0[jj] = fmaf(a4u, fabsf(l0 + r), acc0[jj]);
                }
            }
        }
        // no barrier: next iter's commit/MFMA touch the other buffer; ring
        // safety follows from the 2 barriers above (ordering argument in notes)
    }

    // ---- softmax over j (row = i_base+iq lives in one 32-lane half-wave) ----
    {
        const v4f bi = *(const v4f*)(bias + (i_base + iq) * 128 + j0);
        float ev[4];
        #pragma unroll
        for (int jj = 0; jj < 4; ++jj)
            ev[jj] = acc0[jj] + dl0 + dr[jj] + bi[jj];
        float m_ = fmaxf(fmaxf(ev[0], ev[1]), fmaxf(ev[2], ev[3]));
        #pragma unroll
        for (int d_ = 1; d_ <= 16; d_ <<= 1) m_ = fmaxf(m_, __shfl_xor(m_, d_));
        float p0 = __expf(ev[0] - m_), p1 = __expf(ev[1] - m_);
        float p2 = __expf(ev[2] - m_), p3 = __expf(ev[3] - m_);
        float s_ = p0 + p1 + p2 + p3;
        #pragma unroll
        for (int d_ = 1; d_ <= 16; d_ <<= 1) s_ += __shfl_xor(s_, d_);
        const float inv_ = 1.f / s_;
        *(v4f*)&att[iq * 132 + j0] = (v4f){p0 * inv_, p1 * inv_, p2 * inv_, p3 * inv_};
    }
    __syncthreads();

    // ---- phase 2: out[b][w][i] = sigmoid(sum_j att[i][j]*x[b][w][j]) ----
    // thread: w = t>>1 (1 w), i4 = (t&1)*4 (4 i). x from bf16 xT.
    const int wq = t >> 1;
    const int i4 = (t & 1) * 4;
    const int hs = wq & 1;                 // halfword select
    float o[4] = {};
    #pragma unroll 4
    for (int jc = 0; jc < 32; ++jc) {
        v4f av[4];
        #pragma unroll
        for (int q = 0; q < 4; ++q)
            av[q] = *(const v4f*)&att[(i4 + q) * 132 + jc * 4];
        float xv[4];
        #pragma unroll
        for (int u = 0; u < 4; ++u) {
            const int k = jc * 4 + u;
            const int gs = (wq >> 3) ^ ((k >> 3) & 15);
            const unsigned pp = *(const unsigned*)&xT[k * 136 + (gs << 3) + (wq & 6)];
            xv[u] = bf2f(hs ? (pp >> 16) : (pp & 0xFFFFu));
        }
        #pragma unroll
        for (int u = 0; u < 4; ++u)
            #pragma unroll
            for (int q = 0; q < 4; ++q)
                o[q] = fmaf(xv[u], av[q][u], o[q]);
    }
    {
        v4f r;
        r[0] = 1.f / (1.f + __expf(-o[0]));
        r[1] = 1.f / (1.f + __expf(-o[1]));
        r[2] = 1.f / (1.f + __expf(-o[2]));
        r[3] = 1.f / (1.f + __expf(-o[3]));
        *(v4f*)(out + (size_t)b * 16384 + wq * 128 + i_base + i4) = r;
    }
}

extern "C" void kernel_launch(void* const* d_in, const int* in_sizes, int n_in,
                              void* d_out, int out_size, void* d_ws, size_t ws_size,
                              hipStream_t stream) {
    const float* x     = (const float*)d_in[0];
    const float* lin_w = (const float*)d_in[1];
    const float* lin_b = (const float*)d_in[2];
    const float* a     = (const float*)d_in[3];
    const float* bias  = (const float*)d_in[4];
    float* out = (float*)d_out;
    (void)d_ws; (void)ws_size;

    k_fused<<<dim3(32, 16), 256, 0, stream>>>(x, lin_w, lin_b, a, bias, out);
}

// Round 14
// 32.483 us; speedup vs baseline: 1.4435x; 1.4435x over previous
//
#include <hip/hip_runtime.h>

// FeatureAttentionLayer: B=32, W=128, K=128, E=256, fp32.
//   L[i][e] = sum_w x[b][w][i]*lin_w[e][w] + lin_b[e]
//   R[j][e] = sum_w x[b][w][j]*lin_w[e][128+w]
//   e[i][j] = 0.6(dL[i]+dR[j]) + sum_e 0.4a[e]|L+R| + bias   (LReLU identity)
//   att = softmax_j; out[b][w][i] = sigmoid(sum_j att[i][j]*x[b][w][j])
//
// ws: P[b][r][k] (r<256: L^T rows +lin_b; r>=256: R^T rows), 2M floats; a6/a4 @ 2M.
// Round-14: r13 counters: VALU 44% / MFMA 5% / conflicts 3M / FETCH tiny ->
// instruction-count-bound, not memory. New minimal-instruction K1:
//  - A-frags loaded global->reg->pack directly (no As staging/barrier/ds_read)
//  - only xT (true transpose) staged in LDS; k-split halves it (17KB)
//  - stores via 2-way-free LDS bounce -> coalesced v4f (was 32x scalar scatter)
//  - 2 barriers, 16 MFMA/wave, ~500 wave-instr/block. 2 blocks/CU.
// K2 = byte-identical verified 6us kernel. If total still ~30+: external floor.

typedef float v2f __attribute__((ext_vector_type(2)));
typedef float v4f __attribute__((ext_vector_type(4)));
typedef short bf16x8 __attribute__((ext_vector_type(8)));

#define WS_A6  2097152
#define WS_A4  (2097152 + 256)

__device__ __forceinline__ unsigned pack_bf16x2(float a, float b) {
    unsigned ua = __builtin_bit_cast(unsigned, a);
    unsigned ub = __builtin_bit_cast(unsigned, b);
    ua = (ua + 0x7FFFu + ((ua >> 16) & 1u)) >> 16;   // RNE f32->bf16
    ub = (ub + 0x7FFFu + ((ub >> 16) & 1u)) >> 16;
    return ua | (ub << 16);
}

// ---------------- K1: projection GEMM, minimal instructions ----------------
// grid (32 b, 8 rt, 2 kt), 256 thr (4 waves), ~35 KB LDS -> 2+ blocks/CU.
// Block output: 64 r x 64 k of P. Wave: 16 r x 64 k.
__global__ __launch_bounds__(256) void k_linear(
    const float* __restrict__ x, const float* __restrict__ lin_w,
    const float* __restrict__ lin_b, const float* __restrict__ a,
    float* __restrict__ ws)
{
    __shared__ unsigned short xT[64 * 136];   // bf16 x[b][w][k-half] T+swz (17.4 KB)
    __shared__ float Ps[64 * 68];             // f32 store bounce (17.4 KB)

    const int t = threadIdx.x;
    const int b = blockIdx.x, rt = blockIdx.y, kt = blockIdx.z;
    const int r0 = rt * 64, k0 = kt * 64;
    const bool isL = (rt < 4);

    if (b == 0 && rt == 0 && kt == 0) {       // fold a once (K2 stream-ordered after)
        float av = a[t];
        ws[WS_A6 + t] = 0.6f * av;
        ws[WS_A4 + t] = 0.4f * av;
    }

    // ---- stage xT[kk][w'] = bf16(x[b][w][k0+kk]), swizzle g ^= (kk>>3)&15 ----
    {
        const float* xg = x + b * 16384 + k0;
        #pragma unroll
        for (int q = 0; q < 4; ++q) {
            const int idx = t + q * 256;                  // 0..1023
            const int wp = idx >> 4;                      // w-pair 0..63
            const int k4 = (idx & 15) << 2;               // 0..60
            const v4f r0v = *(const v4f*)(xg + (2 * wp) * 128 + k4);
            const v4f r1v = *(const v4f*)(xg + (2 * wp + 1) * 128 + k4);
            const int g   = wp >> 2;
            const int off = (2 * wp) & 7;
            #pragma unroll
            for (int u = 0; u < 4; ++u) {
                const int kk = k4 + u;
                const int gs = g ^ ((kk >> 3) & 15);
                *(unsigned*)&xT[kk * 136 + (gs << 3) + off] = pack_bf16x2(r0v[u], r1v[u]);
            }
        }
    }
    __syncthreads();

    // ---- A-frags: global -> reg -> bf16 pack (no LDS round-trip) ----
    const int l = t & 63, wave = t >> 6;
    const int lr = l & 15, lg = l >> 4;
    const int rr_a = wave * 16 + lr;                      // A-frag row (r-local)
    const int r_g  = r0 + rr_a;
    const float* Arow = isL ? (lin_w + (size_t)r_g * 256)
                            : (lin_w + (size_t)(r_g - 256) * 256 + 128);
    bf16x8 af[4];
    #pragma unroll
    for (int kc = 0; kc < 4; ++kc) {
        const v4f a0 = *(const v4f*)(Arow + kc * 32 + lg * 8);
        const v4f a1 = *(const v4f*)(Arow + kc * 32 + lg * 8 + 4);
        unsigned p0 = pack_bf16x2(a0[0], a0[1]), p1 = pack_bf16x2(a0[2], a0[3]);
        unsigned p2 = pack_bf16x2(a1[0], a1[1]), p3 = pack_bf16x2(a1[2], a1[3]);
        af[kc] = __builtin_bit_cast(bf16x8, (uint4){p0, p1, p2, p3});
    }

    // ---- MFMA: 4 nf x 4 kc; B rows kk = nf*16+lr (r11-verified layout) ----
    v4f acc[4];
    #pragma unroll
    for (int nf = 0; nf < 4; ++nf) acc[nf] = (v4f){0.f, 0.f, 0.f, 0.f};
    #pragma unroll
    for (int nf = 0; nf < 4; ++nf) {
        const int kk = nf * 16 + lr;
        const int vr = (kk >> 3) & 15;
        #pragma unroll
        for (int kc = 0; kc < 4; ++kc) {
            const bf16x8 bfv = *(const bf16x8*)&xT[kk * 136 + (((kc * 4 + lg) ^ vr) << 3)];
            acc[nf] = __builtin_amdgcn_mfma_f32_16x16x32_bf16(af[kc], bfv, acc[nf], 0, 0, 0);
        }
    }

    // ---- bounce: Ps[rr][kk]; writes 2-way (free), then coalesced v4f stores ----
    #pragma unroll
    for (int nf = 0; nf < 4; ++nf)
        #pragma unroll
        for (int j = 0; j < 4; ++j)
            Ps[(wave * 16 + lg * 4 + j) * 68 + nf * 16 + lr] = acc[nf][j];
    __syncthreads();

    #pragma unroll
    for (int q = 0; q < 4; ++q) {
        const int idx = t + q * 256;                      // 0..1023
        const int rr = idx >> 4, k4 = (idx & 15) << 2;
        const float lb = isL ? lin_b[r0 + rr] : 0.f;
        const v4f v = *(const v4f*)&Ps[rr * 68 + k4];
        float* dst = ws + ((size_t)(b * 512 + r0 + rr) * 128 + k0 + k4);
        *(v4f*)dst = (v4f){v[0] + lb, v[1] + lb, v[2] + lb, v[3] + lb};
    }
}

// ---------------- K2: logits + softmax + PV + sigmoid (verified ~6us, unchanged) ----------------
__global__ __launch_bounds__(256, 1) void k_attn(
    const float* __restrict__ x, const float* __restrict__ bias,
    const float* __restrict__ ws, float* __restrict__ out)
{
    __shared__ float Rs[2][8192];      // 64 KB; reused as xT after e-loop
    __shared__ float Lt[256 * 16];     // 16 KB: Lt[e*16+il]
    __shared__ float att[16 * 132];    // 8.4 KB
    __shared__ float as6[256], as4[256];

    const int t = threadIdx.x;
    const int b = blockIdx.x, it = blockIdx.y;
    const float* Pb = ws + (size_t)b * 65536;
    const float* Rsrc = Pb + 32768;    // R^T rows, contiguous 32 KB per chunk

    v4f rx[8];
#define RLOAD(n_) do { const float* s_ = Rsrc + (n_) * 8192 + t * 4;  \
    _Pragma("unroll") for (int q = 0; q < 8; ++q)                     \
      rx[q] = *(const v4f*)(s_ + q * 1024); } while (0)

    RLOAD(0);

    // stage L^T tile (coalesced) + a-vectors
    {
        const float* Ls = Pb + it * 16;
        #pragma unroll
        for (int q = 0; q < 4; ++q) {
            const int idx = t + q * 256;
            const int e = idx >> 2, il4 = (idx & 3) * 4;
            *(v4f*)&Lt[e * 16 + il4] = *(const v4f*)(Ls + e * 128 + il4);
        }
    }
    as6[t] = ws[WS_A6 + t];
    as4[t] = ws[WS_A4 + t];

    const int jp = t & 31, iq = t >> 5;
    const int j0 = jp * 4, il0 = iq * 2;

    float acc0[4] = {}, acc1[4] = {};      // sum 0.4a*|L+R| per jj, rows il0/il0+1
    float dr[4] = {};                      // sum 0.6a*R per jj
    float dl0 = 0.f, dl1 = 0.f;            // sum 0.6a*L per row

    #pragma unroll 1
    for (int n = 0; n < 4; ++n) {
        float* rs = &Rs[n & 1][0];
        {   // commit staged chunk n to LDS (linear, conflict-free sweep)
            float* d_ = rs + t * 4;
            #pragma unroll
            for (int q = 0; q < 8; ++q) *(v4f*)(d_ + q * 1024) = rx[q];
        }
        if (n < 3) RLOAD(n + 1);           // global latency covered by compute below
        __syncthreads();

        const int eg0 = n * 64;
        #pragma unroll
        for (int g = 0; g < 16; ++g) {
            const int e0 = g * 4, eg = eg0 + e0;
            v4f rv[4]; float2 lv[4];
            #pragma unroll
            for (int u = 0; u < 4; ++u) {
                rv[u] = *(const v4f*)&rs[(e0 + u) * 128 + j0];
                lv[u] = *(const float2*)&Lt[(eg + u) * 16 + il0];
            }
            const v4f a6v = *(const v4f*)&as6[eg];
            const v4f a4v = *(const v4f*)&as4[eg];
            #pragma unroll
            for (int u = 0; u < 4; ++u) {
                const float a6u = a6v[u], a4u = a4v[u];
                const float l0 = lv[u].x, l1 = lv[u].y;
                dl0 = fmaf(a6u, l0, dl0);
                dl1 = fmaf(a6u, l1, dl1);
                #pragma unroll
                for (int jj = 0; jj < 4; ++jj) {
                    const float r = rv[u][jj];
                    dr[jj]   = fmaf(a6u, r, dr[jj]);
                    acc0[jj] = fmaf(a4u, fabsf(l0 + r), acc0[jj]);
                    acc1[jj] = fmaf(a4u, fabsf(l1 + r), acc1[jj]);
                }
            }
        }
    }
    __syncthreads();                       // all waves done with Rs -> reuse as xT

    // stage xT[j][w ^ swz(j)] into the dead R buffers (64 KB exactly).
    float* xT = &Rs[0][0];
    {
        const float* xg = x + b * 16384;
        #pragma unroll
        for (int q = 0; q < 16; ++q) {
            const int idx = t + q * 256;
            const int w = idx >> 5, j4 = (idx & 31) * 4;
            const int s = ((j4 >> 2) & 15) << 1;
            const v4f xv = *(const v4f*)(xg + w * 128 + j4);
            xT[(j4 + 0) * 128 + (w ^ s)] = xv[0];
            xT[(j4 + 1) * 128 + (w ^ s)] = xv[1];
            xT[(j4 + 2) * 128 + (w ^ s)] = xv[2];
            xT[(j4 + 3) * 128 + (w ^ s)] = xv[3];
        }
    }

    // softmax over j (row lives in one 32-lane half-wave)
    const int i0r = it * 16 + il0;
    float ev0[4], ev1[4];
    {
        const v4f b0 = *(const v4f*)(bias + (i0r + 0) * 128 + j0);
        const v4f b1 = *(const v4f*)(bias + (i0r + 1) * 128 + j0);
        #pragma unroll
        for (int jj = 0; jj < 4; ++jj) {
            ev0[jj] = acc0[jj] + dl0 + dr[jj] + b0[jj];
            ev1[jj] = acc1[jj] + dl1 + dr[jj] + b1[jj];
        }
    }
#define SOFTMAX_ROW(EV, ROW) do {                                               \
    float m_ = fmaxf(fmaxf(EV[0], EV[1]), fmaxf(EV[2], EV[3]));                 \
    _Pragma("unroll") for (int d_ = 1; d_ <= 16; d_ <<= 1)                      \
        m_ = fmaxf(m_, __shfl_xor(m_, d_));                                     \
    float p0 = __expf(EV[0] - m_), p1 = __expf(EV[1] - m_);                     \
    float p2 = __expf(EV[2] - m_), p3 = __expf(EV[3] - m_);                     \
    float s_ = p0 + p1 + p2 + p3;                                               \
    _Pragma("unroll") for (int d_ = 1; d_ <= 16; d_ <<= 1)                      \
        s_ += __shfl_xor(s_, d_);                                               \
    const float inv_ = 1.f / s_;                                                \
    *(v4f*)&att[(ROW) * 132 + j0] =                                             \
        (v4f){p0 * inv_, p1 * inv_, p2 * inv_, p3 * inv_}; } while (0)

    SOFTMAX_ROW(ev0, il0 + 0);
    SOFTMAX_ROW(ev1, il0 + 1);
    __syncthreads();

    // phase 2: out[b][w][i] = sigmoid(sum_j att[i][j]*x[b][w][j]); lane 2w x 4i
    const int iq2 = t & 3, wp = t >> 2;
    const int i4 = iq2 * 4, w0 = wp * 2;
    float o[2][4] = {};
    #pragma unroll 4
    for (int jc = 0; jc < 32; ++jc) {
        const int wx = w0 ^ ((jc & 15) << 1);
        v4f av[4]; v2f xv[4];
        #pragma unroll
        for (int q = 0; q < 4; ++q)
            av[q] = *(const v4f*)&att[(i4 + q) * 132 + jc * 4];
        #pragma unroll
        for (int u = 0; u < 4; ++u)
            xv[u] = *(const v2f*)&xT[(jc * 4 + u) * 128 + wx];
        #pragma unroll
        for (int u = 0; u < 4; ++u)
            #pragma unroll
            for (int q = 0; q < 4; ++q) {
                o[0][q] = fmaf(xv[u].x, av[q][u], o[0][q]);
                o[1][q] = fmaf(xv[u].y, av[q][u], o[1][q]);
            }
    }
    #pragma unroll
    for (int w = 0; w < 2; ++w) {
        v4f r;
        r[0] = 1.f / (1.f + __expf(-o[w][0]));
        r[1] = 1.f / (1.f + __expf(-o[w][1]));
        r[2] = 1.f / (1.f + __expf(-o[w][2]));
        r[3] = 1.f / (1.f + __expf(-o[w][3]));
        *(v4f*)(out + (size_t)b * 16384 + (w0 + w) * 128 + it * 16 + i4) = r;
    }
}

extern "C" void kernel_launch(void* const* d_in, const int* in_sizes, int n_in,
                              void* d_out, int out_size, void* d_ws, size_t ws_size,
                              hipStream_t stream) {
    const float* x     = (const float*)d_in[0];
    const float* lin_w = (const float*)d_in[1];
    const float* lin_b = (const float*)d_in[2];
    const float* a     = (const float*)d_in[3];
    const float* bias  = (const float*)d_in[4];
    float* ws  = (float*)d_ws;
    float* out = (float*)d_out;

    k_linear<<<dim3(32, 8, 2), 256, 0, stream>>>(x, lin_w, lin_b, a, ws);
    k_attn  <<<dim3(32, 8), 256, 0, stream>>>(x, bias, ws, out);
}

// Round 15
// 27.419 us; speedup vs baseline: 1.7102x; 1.1847x over previous
//
#include <hip/hip_runtime.h>

// FeatureAttentionLayer: B=32, W=128, K=128, E=256, fp32.
//   L[i][e] = sum_w x[b][w][i]*lin_w[e][w] + lin_b[e]
//   R[j][e] = sum_w x[b][w][j]*lin_w[e][128+w]
//   e[i][j] = 0.6(dL[i]+dR[j]) + sum_e 0.4a[e]|L+R| + bias   (LReLU identity)
//   att = softmax_j; out[b][w][i] = sigmoid(sum_j att[i][j]*x[b][w][j])
//
// ws: P[b][r][k] (r<256: L^T rows +lin_b; r>=256: R^T rows); a6/a4 @ 2M.
// Round-15: first-principles recount showed K2 (not K1) dominates: its e-loop
// is LDS-pipe-bound (2560 LDS instr/CU ~ 10.7us) + phase-2 (~4us). Fix:
//  - E-SPLIT: each wave owns a 16-e slice per chunk (kills 4x duplicate R
//    reads); per-thread tile 8i x 4j; cross-wave reduce in LDS (one-time).
//  - phase-2 via MFMA: att->bf16 (A), x->bf16 [w][j] natural layout (B),
//    r11-verified fragments. 1024 LDS instrs -> ~50 + 8 MFMA/wave.
// K1 = r14 verbatim (passed, minimal).

typedef float v2f __attribute__((ext_vector_type(2)));
typedef float v4f __attribute__((ext_vector_type(4)));
typedef short bf16x8 __attribute__((ext_vector_type(8)));

#define WS_A6  2097152
#define WS_A4  (2097152 + 256)

__device__ __forceinline__ unsigned pack_bf16x2(float a, float b) {
    unsigned ua = __builtin_bit_cast(unsigned, a);
    unsigned ub = __builtin_bit_cast(unsigned, b);
    ua = (ua + 0x7FFFu + ((ua >> 16) & 1u)) >> 16;   // RNE f32->bf16
    ub = (ub + 0x7FFFu + ((ub >> 16) & 1u)) >> 16;
    return ua | (ub << 16);
}

// ---------------- K1: projection GEMM (r14, unchanged) ----------------
__global__ __launch_bounds__(256) void k_linear(
    const float* __restrict__ x, const float* __restrict__ lin_w,
    const float* __restrict__ lin_b, const float* __restrict__ a,
    float* __restrict__ ws)
{
    __shared__ unsigned short xT[64 * 136];
    __shared__ float Ps[64 * 68];

    const int t = threadIdx.x;
    const int b = blockIdx.x, rt = blockIdx.y, kt = blockIdx.z;
    const int r0 = rt * 64, k0 = kt * 64;
    const bool isL = (rt < 4);

    if (b == 0 && rt == 0 && kt == 0) {
        float av = a[t];
        ws[WS_A6 + t] = 0.6f * av;
        ws[WS_A4 + t] = 0.4f * av;
    }

    {
        const float* xg = x + b * 16384 + k0;
        #pragma unroll
        for (int q = 0; q < 4; ++q) {
            const int idx = t + q * 256;
            const int wp = idx >> 4;
            const int k4 = (idx & 15) << 2;
            const v4f r0v = *(const v4f*)(xg + (2 * wp) * 128 + k4);
            const v4f r1v = *(const v4f*)(xg + (2 * wp + 1) * 128 + k4);
            const int g   = wp >> 2;
            const int off = (2 * wp) & 7;
            #pragma unroll
            for (int u = 0; u < 4; ++u) {
                const int kk = k4 + u;
                const int gs = g ^ ((kk >> 3) & 15);
                *(unsigned*)&xT[kk * 136 + (gs << 3) + off] = pack_bf16x2(r0v[u], r1v[u]);
            }
        }
    }
    __syncthreads();

    const int l = t & 63, wave = t >> 6;
    const int lr = l & 15, lg = l >> 4;
    const int rr_a = wave * 16 + lr;
    const int r_g  = r0 + rr_a;
    const float* Arow = isL ? (lin_w + (size_t)r_g * 256)
                            : (lin_w + (size_t)(r_g - 256) * 256 + 128);
    bf16x8 af[4];
    #pragma unroll
    for (int kc = 0; kc < 4; ++kc) {
        const v4f a0 = *(const v4f*)(Arow + kc * 32 + lg * 8);
        const v4f a1 = *(const v4f*)(Arow + kc * 32 + lg * 8 + 4);
        unsigned p0 = pack_bf16x2(a0[0], a0[1]), p1 = pack_bf16x2(a0[2], a0[3]);
        unsigned p2 = pack_bf16x2(a1[0], a1[1]), p3 = pack_bf16x2(a1[2], a1[3]);
        af[kc] = __builtin_bit_cast(bf16x8, (uint4){p0, p1, p2, p3});
    }

    v4f acc[4];
    #pragma unroll
    for (int nf = 0; nf < 4; ++nf) acc[nf] = (v4f){0.f, 0.f, 0.f, 0.f};
    #pragma unroll
    for (int nf = 0; nf < 4; ++nf) {
        const int kk = nf * 16 + lr;
        const int vr = (kk >> 3) & 15;
        #pragma unroll
        for (int kc = 0; kc < 4; ++kc) {
            const bf16x8 bfv = *(const bf16x8*)&xT[kk * 136 + (((kc * 4 + lg) ^ vr) << 3)];
            acc[nf] = __builtin_amdgcn_mfma_f32_16x16x32_bf16(af[kc], bfv, acc[nf], 0, 0, 0);
        }
    }

    #pragma unroll
    for (int nf = 0; nf < 4; ++nf)
        #pragma unroll
        for (int j = 0; j < 4; ++j)
            Ps[(wave * 16 + lg * 4 + j) * 68 + nf * 16 + lr] = acc[nf][j];
    __syncthreads();

    #pragma unroll
    for (int q = 0; q < 4; ++q) {
        const int idx = t + q * 256;
        const int rr = idx >> 4, k4 = (idx & 15) << 2;
        const float lb = isL ? lin_b[r0 + rr] : 0.f;
        const v4f v = *(const v4f*)&Ps[rr * 68 + k4];
        float* dst = ws + ((size_t)(b * 512 + r0 + rr) * 128 + k0 + k4);
        *(v4f*)dst = (v4f){v[0] + lb, v[1] + lb, v[2] + lb, v[3] + lb};
    }
}

// ---------------- K2: e-split logits + softmax + MFMA-PV ----------------
// grid (32 b, 8 it of 16 i-rows), 256 thr (4 waves).
// S layout (f32 idx): RS0 0 | RS1 8192 | LT 16384 (256x16) | A6 20480 |
// A4 20736 | DLR 20992 (4x16) | DRR 21056 (4x128) | ATT 21568 (16x68 u32).
// Overlays: red4[4][16][128] on RS0 (post e-loop); xbf[128][68]u32 on RS1+
// spill into dead LT (8704 u32 <= 8192+4096).
#define RS0 0
#define RS1 8192
#define LT  16384
#define A6  20480
#define A4  20736
#define DLR 20992
#define DRR 21056
#define ATT 21568

__global__ __launch_bounds__(256) void k_attn(
    const float* __restrict__ x, const float* __restrict__ bias,
    const float* __restrict__ ws, float* __restrict__ out)
{
    __shared__ __align__(16) float S[22656];   // 88.5 KB

    const int t = threadIdx.x;
    const int b = blockIdx.x, it = blockIdx.y;
    const float* Pb = ws + (size_t)b * 65536;
    const float* Rsrc = Pb + 32768;

    v4f rx[8];
#define RLOAD(n_) do { const float* s_ = Rsrc + (n_) * 8192 + t * 4;  \
    _Pragma("unroll") for (int q = 0; q < 8; ++q)                     \
      rx[q] = *(const v4f*)(s_ + q * 1024); } while (0)

    RLOAD(0);

    {   // stage L^T tile [256 e][16 i] (coalesced) + a-vectors
        const float* Ls = Pb + it * 16;
        #pragma unroll
        for (int q = 0; q < 4; ++q) {
            const int idx = t + q * 256;
            const int e = idx >> 2, il4 = (idx & 3) * 4;
            *(v4f*)&S[LT + e * 16 + il4] = *(const v4f*)(Ls + e * 128 + il4);
        }
    }
    S[A6 + t] = ws[WS_A6 + t];
    S[A4 + t] = ws[WS_A4 + t];

    const int l = t & 63, wv = t >> 6;
    const int jl = l & 31, il = l >> 5;        // e-loop lanes: 32 j x 2 i-oct
    const int j0e = jl * 4;

    float acc[8][4] = {};                      // [i-sub][jj]  0.4a*|L+R|
    float dle[8] = {};                         // 0.6a*L per i-sub (this wave's e)
    float dre[4] = {};                         // 0.6a*R per jj

    #pragma unroll 1
    for (int c = 0; c < 4; ++c) {
        const int cur = c & 1;
        {   // commit chunk to Rs[cur]
            float* d_ = &S[RS0 + cur * 8192] + t * 4;
            #pragma unroll
            for (int q = 0; q < 8; ++q) *(v4f*)(d_ + q * 1024) = rx[q];
        }
        if (c < 3) RLOAD(c + 1);
        __syncthreads();

        const float* rs = &S[RS0 + cur * 8192];
        #pragma unroll
        for (int g = 0; g < 4; ++g) {
            const int er = wv * 16 + g * 4;    // e-row in chunk (wave's slice)
            const int eg = c * 64 + er;        // global e
            v4f rv[4], lA[4], lB[4];
            #pragma unroll
            for (int u = 0; u < 4; ++u) {
                rv[u] = *(const v4f*)&rs[(er + u) * 128 + j0e];
                lA[u] = *(const v4f*)&S[LT + (eg + u) * 16 + il * 8];
                lB[u] = *(const v4f*)&S[LT + (eg + u) * 16 + il * 8 + 4];
            }
            const v4f a6v = *(const v4f*)&S[A6 + eg];
            const v4f a4v = *(const v4f*)&S[A4 + eg];
            #pragma unroll
            for (int u = 0; u < 4; ++u) {
                const float a6u = a6v[u], a4u = a4v[u];
                #pragma unroll
                for (int q = 0; q < 4; ++q) {
                    const float la = lA[u][q], lb2 = lB[u][q];
                    dle[q]     = fmaf(a6u, la,  dle[q]);
                    dle[4 + q] = fmaf(a6u, lb2, dle[4 + q]);
                    #pragma unroll
                    for (int jj = 0; jj < 4; ++jj) {
                        const float r = rv[u][jj];
                        acc[q][jj]     = fmaf(a4u, fabsf(la  + r), acc[q][jj]);
                        acc[4 + q][jj] = fmaf(a4u, fabsf(lb2 + r), acc[4 + q][jj]);
                    }
                }
                #pragma unroll
                for (int jj = 0; jj < 4; ++jj)
                    dre[jj] = fmaf(a6u, rv[u][jj], dre[jj]);
            }
        }
    }

    // ---- cross-wave partials -> red4 (overlays RS0; safe: c=3 used RS1) ----
    {
        float* red = &S[RS0];
        #pragma unroll
        for (int q = 0; q < 8; ++q)
            *(v4f*)&red[wv * 2048 + (il * 8 + q) * 128 + j0e] =
                (v4f){acc[q][0], acc[q][1], acc[q][2], acc[q][3]};
        if (jl == 0) {
            *(v4f*)&S[DLR + wv * 16 + il * 8]     = (v4f){dle[0], dle[1], dle[2], dle[3]};
            *(v4f*)&S[DLR + wv * 16 + il * 8 + 4] = (v4f){dle[4], dle[5], dle[6], dle[7]};
        }
        if (il == 0)
            *(v4f*)&S[DRR + wv * 128 + j0e] = (v4f){dre[0], dre[1], dre[2], dre[3]};
    }

    // issue xbf global loads BEFORE barrier (latency hides under it)
    v4f xr[16];
    {
        const float* xg = x + b * 16384;
        #pragma unroll
        for (int q = 0; q < 8; ++q) {
            const int idx = t + q * 256;               // 0..2047
            const int w = idx >> 4, j8 = (idx & 15) * 8;
            xr[2 * q]     = *(const v4f*)(xg + w * 128 + j8);
            xr[2 * q + 1] = *(const v4f*)(xg + w * 128 + j8 + 4);
        }
    }
    __syncthreads();                                   // red4/dlr/drr ready; RS1 free

    // commit xbf[w][j] bf16 (u32 pairs) onto RS1 (+spill into dead LT)
    unsigned* ubf = (unsigned*)&S[RS1];
    #pragma unroll
    for (int q = 0; q < 8; ++q) {
        const int idx = t + q * 256;
        const int w = idx >> 4, jh = (idx & 15) * 4;   // u32 col
        const v4f x0 = xr[2 * q], x1 = xr[2 * q + 1];
        uint4 pk;
        pk.x = pack_bf16x2(x0[0], x0[1]);  pk.y = pack_bf16x2(x0[2], x0[3]);
        pk.z = pack_bf16x2(x1[0], x1[1]);  pk.w = pack_bf16x2(x1[2], x1[3]);
        *(uint4*)&ubf[w * 68 + jh] = pk;
    }

    // ---- softmax (thread: 2 i x 4 j; row in one 32-lane half-wave) ----
    {
        const int jps = t & 31, iqs = t >> 5;
        const int j0s = jps * 4, il0 = iqs * 2;
        const int i0 = it * 16;
        const float* red = &S[RS0];
        v4f drs = *(const v4f*)&S[DRR + j0s];
        drs += *(const v4f*)&S[DRR + 128 + j0s];
        drs += *(const v4f*)&S[DRR + 256 + j0s];
        drs += *(const v4f*)&S[DRR + 384 + j0s];
        unsigned* attu = (unsigned*)&S[ATT];
        #pragma unroll
        for (int ii = 0; ii < 2; ++ii) {
            const int i = il0 + ii;
            v4f sm = *(const v4f*)&red[i * 128 + j0s];
            sm += *(const v4f*)&red[2048 + i * 128 + j0s];
            sm += *(const v4f*)&red[4096 + i * 128 + j0s];
            sm += *(const v4f*)&red[6144 + i * 128 + j0s];
            const float dls = S[DLR + i] + S[DLR + 16 + i] + S[DLR + 32 + i] + S[DLR + 48 + i];
            const v4f bi = *(const v4f*)(bias + (i0 + i) * 128 + j0s);
            float ev[4];
            #pragma unroll
            for (int jj = 0; jj < 4; ++jj) ev[jj] = sm[jj] + dls + drs[jj] + bi[jj];
            float m_ = fmaxf(fmaxf(ev[0], ev[1]), fmaxf(ev[2], ev[3]));
            #pragma unroll
            for (int d = 1; d <= 16; d <<= 1) m_ = fmaxf(m_, __shfl_xor(m_, d));
            float p0 = __expf(ev[0] - m_), p1 = __expf(ev[1] - m_);
            float p2 = __expf(ev[2] - m_), p3 = __expf(ev[3] - m_);
            float s_ = p0 + p1 + p2 + p3;
            #pragma unroll
            for (int d = 1; d <= 16; d <<= 1) s_ += __shfl_xor(s_, d);
            const float inv = 1.f / s_;
            attu[i * 68 + jps * 2]     = pack_bf16x2(p0 * inv, p1 * inv);
            attu[i * 68 + jps * 2 + 1] = pack_bf16x2(p2 * inv, p3 * inv);
        }
    }
    __syncthreads();                                   // att_bf + xbf ready

    // ---- PV via MFMA: out[w][i] = sum_j att[i][j] x[w][j]; D: m=i, n=w ----
    {
        const int lr = l & 15, lg = l >> 4;
        const int i0 = it * 16;
        const unsigned* attu = (const unsigned*)&S[ATT];
        bf16x8 paf[4];
        #pragma unroll
        for (int kc = 0; kc < 4; ++kc)
            paf[kc] = *(const bf16x8*)&attu[lr * 68 + kc * 16 + lg * 4];
        #pragma unroll
        for (int nf = 0; nf < 2; ++nf) {
            const int wrow = wv * 32 + nf * 16 + lr;
            v4f pacc = (v4f){0.f, 0.f, 0.f, 0.f};
            #pragma unroll
            for (int kc = 0; kc < 4; ++kc) {
                const bf16x8 bv = *(const bf16x8*)&ubf[wrow * 68 + kc * 16 + lg * 4];
                pacc = __builtin_amdgcn_mfma_f32_16x16x32_bf16(paf[kc], bv, pacc, 0, 0, 0);
            }
            v4f r;
            r[0] = 1.f / (1.f + __expf(-pacc[0]));
            r[1] = 1.f / (1.f + __expf(-pacc[1]));
            r[2] = 1.f / (1.f + __expf(-pacc[2]));
            r[3] = 1.f / (1.f + __expf(-pacc[3]));
            *(v4f*)(out + (size_t)b * 16384 + wrow * 128 + i0 + lg * 4) = r;
        }
    }
}

extern "C" void kernel_launch(void* const* d_in, const int* in_sizes, int n_in,
                              void* d_out, int out_size, void* d_ws, size_t ws_size,
                              hipStream_t stream) {
    const float* x     = (const float*)d_in[0];
    const float* lin_w = (const float*)d_in[1];
    const float* lin_b = (const float*)d_in[2];
    const float* a     = (const float*)d_in[3];
    const float* bias  = (const float*)d_in[4];
    float* ws  = (float*)d_ws;
    float* out = (float*)d_out;

    k_linear<<<dim3(32, 8, 2), 256, 0, stream>>>(x, lin_w, lin_b, a, ws);
    k_attn  <<<dim3(32, 8), 256, 0, stream>>>(x, bias, ws, out);
}

// Round 16
// 25.878 us; speedup vs baseline: 1.8120x; 1.0595x over previous
//
#include <hip/hip_runtime.h>

// FeatureAttentionLayer: B=32, W=128, K=128, E=256, fp32.
//   L[i][e] = sum_w x[b][w][i]*lin_w[e][w] + lin_b[e]
//   R[j][e] = sum_w x[b][w][j]*lin_w[e][128+w]
//   e[i][j] = 0.6(dL[i]+dR[j]) + sum_e 0.4a[e]|L+R| + bias   (LReLU identity)
//   att = softmax_j; out[b][w][i] = sigmoid(sum_j att[i][j]*x[b][w][j])
//
// ws: P[b][r][k] (r<256: L^T rows +lin_b; r>=256: R^T rows); a6/a4 @ 2M.
// Round-16: r15's K2 ran 256 thr / 1 block/CU = 1 WAVE/SIMD (round-1 disease
// relocated). This round: 512 thr (8 waves = 2/SIMD), 8-way e-split chosen so
// LDS-pipe instrs stay exactly 896/CU and VALU total is unchanged — pure
// latency-hiding gain. red = 8 partials (64KB) overlays both dead RS buffers;
// xbf overlays RS1 after softmax. K1 = r14 verbatim (passed twice).

typedef float v2f __attribute__((ext_vector_type(2)));
typedef float v4f __attribute__((ext_vector_type(4)));
typedef short bf16x8 __attribute__((ext_vector_type(8)));

#define WS_A6  2097152
#define WS_A4  (2097152 + 256)

__device__ __forceinline__ unsigned pack_bf16x2(float a, float b) {
    unsigned ua = __builtin_bit_cast(unsigned, a);
    unsigned ub = __builtin_bit_cast(unsigned, b);
    ua = (ua + 0x7FFFu + ((ua >> 16) & 1u)) >> 16;   // RNE f32->bf16
    ub = (ub + 0x7FFFu + ((ub >> 16) & 1u)) >> 16;
    return ua | (ub << 16);
}

// ---------------- K1: projection GEMM (r14, unchanged) ----------------
__global__ __launch_bounds__(256) void k_linear(
    const float* __restrict__ x, const float* __restrict__ lin_w,
    const float* __restrict__ lin_b, const float* __restrict__ a,
    float* __restrict__ ws)
{
    __shared__ unsigned short xT[64 * 136];
    __shared__ float Ps[64 * 68];

    const int t = threadIdx.x;
    const int b = blockIdx.x, rt = blockIdx.y, kt = blockIdx.z;
    const int r0 = rt * 64, k0 = kt * 64;
    const bool isL = (rt < 4);

    if (b == 0 && rt == 0 && kt == 0) {
        float av = a[t];
        ws[WS_A6 + t] = 0.6f * av;
        ws[WS_A4 + t] = 0.4f * av;
    }

    {
        const float* xg = x + b * 16384 + k0;
        #pragma unroll
        for (int q = 0; q < 4; ++q) {
            const int idx = t + q * 256;
            const int wp = idx >> 4;
            const int k4 = (idx & 15) << 2;
            const v4f r0v = *(const v4f*)(xg + (2 * wp) * 128 + k4);
            const v4f r1v = *(const v4f*)(xg + (2 * wp + 1) * 128 + k4);
            const int g   = wp >> 2;
            const int off = (2 * wp) & 7;
            #pragma unroll
            for (int u = 0; u < 4; ++u) {
                const int kk = k4 + u;
                const int gs = g ^ ((kk >> 3) & 15);
                *(unsigned*)&xT[kk * 136 + (gs << 3) + off] = pack_bf16x2(r0v[u], r1v[u]);
            }
        }
    }
    __syncthreads();

    const int l = t & 63, wave = t >> 6;
    const int lr = l & 15, lg = l >> 4;
    const int rr_a = wave * 16 + lr;
    const int r_g  = r0 + rr_a;
    const float* Arow = isL ? (lin_w + (size_t)r_g * 256)
                            : (lin_w + (size_t)(r_g - 256) * 256 + 128);
    bf16x8 af[4];
    #pragma unroll
    for (int kc = 0; kc < 4; ++kc) {
        const v4f a0 = *(const v4f*)(Arow + kc * 32 + lg * 8);
        const v4f a1 = *(const v4f*)(Arow + kc * 32 + lg * 8 + 4);
        unsigned p0 = pack_bf16x2(a0[0], a0[1]), p1 = pack_bf16x2(a0[2], a0[3]);
        unsigned p2 = pack_bf16x2(a1[0], a1[1]), p3 = pack_bf16x2(a1[2], a1[3]);
        af[kc] = __builtin_bit_cast(bf16x8, (uint4){p0, p1, p2, p3});
    }

    v4f acc[4];
    #pragma unroll
    for (int nf = 0; nf < 4; ++nf) acc[nf] = (v4f){0.f, 0.f, 0.f, 0.f};
    #pragma unroll
    for (int nf = 0; nf < 4; ++nf) {
        const int kk = nf * 16 + lr;
        const int vr = (kk >> 3) & 15;
        #pragma unroll
        for (int kc = 0; kc < 4; ++kc) {
            const bf16x8 bfv = *(const bf16x8*)&xT[kk * 136 + (((kc * 4 + lg) ^ vr) << 3)];
            acc[nf] = __builtin_amdgcn_mfma_f32_16x16x32_bf16(af[kc], bfv, acc[nf], 0, 0, 0);
        }
    }

    #pragma unroll
    for (int nf = 0; nf < 4; ++nf)
        #pragma unroll
        for (int j = 0; j < 4; ++j)
            Ps[(wave * 16 + lg * 4 + j) * 68 + nf * 16 + lr] = acc[nf][j];
    __syncthreads();

    #pragma unroll
    for (int q = 0; q < 4; ++q) {
        const int idx = t + q * 256;
        const int rr = idx >> 4, k4 = (idx & 15) << 2;
        const float lb = isL ? lin_b[r0 + rr] : 0.f;
        const v4f v = *(const v4f*)&Ps[rr * 68 + k4];
        float* dst = ws + ((size_t)(b * 512 + r0 + rr) * 128 + k0 + k4);
        *(v4f*)dst = (v4f){v[0] + lb, v[1] + lb, v[2] + lb, v[3] + lb};
    }
}

// ---------------- K2: 512-thr, 8-wave e-split + softmax + MFMA-PV ----------------
// grid (32 b, 8 it of 16 i-rows), 512 thr (8 waves = 2/SIMD).
// S (f32 idx): RS0 0 | RS1 8192 | LT 16384 (256x16) | A6 20480 | A4 20736 |
// DLR 20992 (8x16) | DRR 21120 (8x128) | ATT 22144 (16x68 u32). ~90.8 KB.
// Overlays: red[8][16][128] on RS0+RS1 (post e-loop);
//           xbf[128][68]u32 on RS1 + LT head (post softmax).
#define RS0 0
#define RS1 8192
#define LT  16384
#define A6  20480
#define A4  20736
#define DLR 20992
#define DRR 21120
#define ATT 22144

__global__ __launch_bounds__(512) void k_attn(
    const float* __restrict__ x, const float* __restrict__ bias,
    const float* __restrict__ ws, float* __restrict__ out)
{
    __shared__ __align__(16) float S[23232];   // 90.75 KB

    const int t = threadIdx.x;
    const int b = blockIdx.x, it = blockIdx.y;
    const float* Pb = ws + (size_t)b * 65536;
    const float* Rsrc = Pb + 32768;

    v4f rx[4];
#define RLOAD(n_) do { const float* s_ = Rsrc + (n_) * 8192 + t * 4;  \
    _Pragma("unroll") for (int q = 0; q < 4; ++q)                     \
      rx[q] = *(const v4f*)(s_ + q * 2048); } while (0)

    RLOAD(0);

    {   // stage L^T tile [256 e][16 i] (coalesced)
        const float* Ls = Pb + it * 16;
        #pragma unroll
        for (int q = 0; q < 2; ++q) {
            const int idx = t + q * 512;
            const int e = idx >> 2, il4 = (idx & 3) * 4;
            *(v4f*)&S[LT + e * 16 + il4] = *(const v4f*)(Ls + e * 128 + il4);
        }
    }
    if (t < 256) S[A6 + t] = ws[WS_A6 + t];
    else         S[A4 + (t - 256)] = ws[WS_A4 + (t - 256)];

    const int l = t & 63, wv = t >> 6;         // wv = e-slice owner (8 slices)
    const int jl = l & 31, il = l >> 5;        // thread: 4 j x 8 i (il-half of 16)
    const int j0e = jl * 4;

    float acc[8][4] = {};                      // [i-sub][jj]  0.4a*|L+R|
    float dle[8] = {};                         // 0.6a*L per i-sub (wave's e-slice)
    float dre[4] = {};                         // 0.6a*R per jj   (wave's e-slice)

    #pragma unroll 1
    for (int c = 0; c < 4; ++c) {
        const int cur = c & 1;
        {   // commit chunk c (64 e x 128 j) to RS[cur]
            float* d_ = &S[RS0 + cur * 8192] + t * 4;
            #pragma unroll
            for (int q = 0; q < 4; ++q) *(v4f*)(d_ + q * 2048) = rx[q];
        }
        if (c < 3) RLOAD(c + 1);
        __syncthreads();

        const float* rs = &S[RS0 + cur * 8192];
        #pragma unroll
        for (int g = 0; g < 2; ++g) {
            const int er = wv * 8 + g * 4;     // e-row in chunk (wave's slice)
            const int eg = c * 64 + er;        // global e
            v4f rv[4], lA[4], lB[4];
            #pragma unroll
            for (int u = 0; u < 4; ++u) {
                rv[u] = *(const v4f*)&rs[(er + u) * 128 + j0e];
                lA[u] = *(const v4f*)&S[LT + (eg + u) * 16 + il * 8];
                lB[u] = *(const v4f*)&S[LT + (eg + u) * 16 + il * 8 + 4];
            }
            const v4f a6v = *(const v4f*)&S[A6 + eg];
            const v4f a4v = *(const v4f*)&S[A4 + eg];
            #pragma unroll
            for (int u = 0; u < 4; ++u) {
                const float a6u = a6v[u], a4u = a4v[u];
                #pragma unroll
                for (int q = 0; q < 4; ++q) {
                    const float la = lA[u][q], lb2 = lB[u][q];
                    dle[q]     = fmaf(a6u, la,  dle[q]);
                    dle[4 + q] = fmaf(a6u, lb2, dle[4 + q]);
                    #pragma unroll
                    for (int jj = 0; jj < 4; ++jj) {
                        const float r = rv[u][jj];
                        acc[q][jj]     = fmaf(a4u, fabsf(la  + r), acc[q][jj]);
                        acc[4 + q][jj] = fmaf(a4u, fabsf(lb2 + r), acc[4 + q][jj]);
                    }
                }
                #pragma unroll
                for (int jj = 0; jj < 4; ++jj)
                    dre[jj] = fmaf(a6u, rv[u][jj], dre[jj]);
            }
        }
    }
    __syncthreads();                           // all waves done reading RS0/RS1

    // ---- partials -> red[8][16][128] over RS0+RS1; DLR/DRR ----
    {
        float* red = &S[RS0];
        #pragma unroll
        for (int q = 0; q < 8; ++q)
            *(v4f*)&red[wv * 2048 + (il * 8 + q) * 128 + j0e] =
                (v4f){acc[q][0], acc[q][1], acc[q][2], acc[q][3]};
        if (jl == 0) {
            *(v4f*)&S[DLR + wv * 16 + il * 8]     = (v4f){dle[0], dle[1], dle[2], dle[3]};
            *(v4f*)&S[DLR + wv * 16 + il * 8 + 4] = (v4f){dle[4], dle[5], dle[6], dle[7]};
        }
        if (il == 0)
            *(v4f*)&S[DRR + wv * 128 + j0e] = (v4f){dre[0], dre[1], dre[2], dre[3]};
    }

    // issue xbf global loads NOW (latency hides under barrier + softmax)
    v4f xr[8];
    {
        const float* xg = x + b * 16384;
        #pragma unroll
        for (int q = 0; q < 4; ++q) {
            const int idx = t + q * 512;               // 0..2047
            const int w = idx >> 4, j8 = (idx & 15) * 8;
            xr[2 * q]     = *(const v4f*)(xg + w * 128 + j8);
            xr[2 * q + 1] = *(const v4f*)(xg + w * 128 + j8 + 4);
        }
    }
    __syncthreads();                                   // red/DLR/DRR ready

    // ---- softmax: thread = (i = t>>5, 4 j = (t&31)*4); row in 32-lane half ----
    {
        const int jps = t & 31, i = t >> 5;            // i in [0,16)
        const int j0s = jps * 4;
        const int i0 = it * 16;
        const float* red = &S[RS0];
        v4f sm = *(const v4f*)&red[i * 128 + j0s];
        v4f drs = *(const v4f*)&S[DRR + j0s];
        float dls = S[DLR + i];
        #pragma unroll
        for (int es = 1; es < 8; ++es) {
            sm  += *(const v4f*)&red[es * 2048 + i * 128 + j0s];
            drs += *(const v4f*)&S[DRR + es * 128 + j0s];
            dls += S[DLR + es * 16 + i];
        }
        const v4f bi = *(const v4f*)(bias + (i0 + i) * 128 + j0s);
        float ev[4];
        #pragma unroll
        for (int jj = 0; jj < 4; ++jj) ev[jj] = sm[jj] + dls + drs[jj] + bi[jj];
        float m_ = fmaxf(fmaxf(ev[0], ev[1]), fmaxf(ev[2], ev[3]));
        #pragma unroll
        for (int d = 1; d <= 16; d <<= 1) m_ = fmaxf(m_, __shfl_xor(m_, d));
        float p0 = __expf(ev[0] - m_), p1 = __expf(ev[1] - m_);
        float p2 = __expf(ev[2] - m_), p3 = __expf(ev[3] - m_);
        float s_ = p0 + p1 + p2 + p3;
        #pragma unroll
        for (int d = 1; d <= 16; d <<= 1) s_ += __shfl_xor(s_, d);
        const float inv = 1.f / s_;
        unsigned* attu = (unsigned*)&S[ATT];
        attu[i * 68 + jps * 2]     = pack_bf16x2(p0 * inv, p1 * inv);
        attu[i * 68 + jps * 2 + 1] = pack_bf16x2(p2 * inv, p3 * inv);
    }
    __syncthreads();                                   // red reads done -> RS1 free

    // ---- commit xbf[w][j] bf16 onto RS1 (+2KB spill into dead LT head) ----
    unsigned* ubf = (unsigned*)&S[RS1];
    #pragma unroll
    for (int q = 0; q < 4; ++q) {
        const int idx = t + q * 512;
        const int w = idx >> 4, jh = (idx & 15) * 4;   // u32 col
        const v4f x0 = xr[2 * q], x1 = xr[2 * q + 1];
        uint4 pk;
        pk.x = pack_bf16x2(x0[0], x0[1]);  pk.y = pack_bf16x2(x0[2], x0[3]);
        pk.z = pack_bf16x2(x1[0], x1[1]);  pk.w = pack_bf16x2(x1[2], x1[3]);
        *(uint4*)&ubf[w * 68 + jh] = pk;
    }
    __syncthreads();                                   // att + xbf ready

    // ---- PV via MFMA: out[w][i] = sum_j att[i][j] x[w][j]; D: m=i, n=w ----
    {
        const int lr = l & 15, lg = l >> 4;
        const int i0 = it * 16;
        const unsigned* attu = (const unsigned*)&S[ATT];
        bf16x8 paf[4];
        #pragma unroll
        for (int kc = 0; kc < 4; ++kc)
            paf[kc] = *(const bf16x8*)&attu[lr * 68 + kc * 16 + lg * 4];
        const int wrow = wv * 16 + lr;                 // 8 waves x 16 = 128 w
        v4f pacc = (v4f){0.f, 0.f, 0.f, 0.f};
        #pragma unroll
        for (int kc = 0; kc < 4; ++kc) {
            const bf16x8 bv = *(const bf16x8*)&ubf[wrow * 68 + kc * 16 + lg * 4];
            pacc = __builtin_amdgcn_mfma_f32_16x16x32_bf16(paf[kc], bv, pacc, 0, 0, 0);
        }
        v4f r;
        r[0] = 1.f / (1.f + __expf(-pacc[0]));
        r[1] = 1.f / (1.f + __expf(-pacc[1]));
        r[2] = 1.f / (1.f + __expf(-pacc[2]));
        r[3] = 1.f / (1.f + __expf(-pacc[3]));
        *(v4f*)(out + (size_t)b * 16384 + wrow * 128 + i0 + lg * 4) = r;
    }
}

extern "C" void kernel_launch(void* const* d_in, const int* in_sizes, int n_in,
                              void* d_out, int out_size, void* d_ws, size_t ws_size,
                              hipStream_t stream) {
    const float* x     = (const float*)d_in[0];
    const float* lin_w = (const float*)d_in[1];
    const float* lin_b = (const float*)d_in[2];
    const float* a     = (const float*)d_in[3];
    const float* bias  = (const float*)d_in[4];
    float* ws  = (float*)d_ws;
    float* out = (float*)d_out;

    k_linear<<<dim3(32, 8, 2), 256, 0, stream>>>(x, lin_w, lin_b, a, ws);
    k_attn  <<<dim3(32, 8), 512, 0, stream>>>(x, bias, ws, out);
}